// Round 1
// baseline (6610.117 us; speedup 1.0000x reference)
//
#include <hip/hip_runtime.h>

// ---------------------------------------------------------------------------
// Persistent 2-layer LSTM, MI355X. Round 12 = Round-11 base + DIRECT GLOBAL
// A-FRAGMENTS + POLL BACKOFF.
// r11 post-mortem: latency-bound (MfmaUtil 7%, VALUBusy 13%); per-step serial
// chain carries two full global->LDS->reg staging round-trips and 8 barriers
// per L1 step. Fix: each lane's MFMA A-fragment is 16 contiguous bytes in the
// published plane (plane + kk*256 + b*32 + q*8), so load it straight from the
// LLC with system-scope loads -> stage_plane + 4 barriers removed from the
// critical path. Out-proj keeps a safe LDS mirror (wave0 ds_write_b128 of its
// already-loaded frags, ordered before the flag1 publish as in r8). Poll loop
// gets graduated s_sleep backoff (1->4->16) to kill the residual 36-45 ms
// poll-storm outlier dispatches. Everything else r8/r11 verbatim: 16 L0-WGs +
// 16 L1-WGs per group, weights in VGPRs/AGPRs, h0 depth-4 / h1 depth-2
// planes, relaxed sc0sc1 LLC ops, per-WG monotone flags, 1 WG/CU pad.
// ---------------------------------------------------------------------------

#define T_STEPS 1024
#define WS_FLAG_OFF 0                     // 8 groups * 128 ints (512 B apart)
#define WS_H0_OFF  4096                   // [8 g][4 depth][16 wg][8 b][32 u] f16
#define WS_H1_OFF  (4096 + 8*4*8192)      // [8 g][2 depth][...]
#define WS_NEED    (WS_H1_OFF + 8*2*8192) // 397312 B (r9/r10/r11 size)

typedef _Float16 f16;
typedef _Float16 f16x8 __attribute__((ext_vector_type(8)));
typedef float    f32x4 __attribute__((ext_vector_type(4)));
typedef unsigned long long u64;

#define HP_STRIDE 520   // padded LDS mirror row stride (f16)

__device__ __forceinline__ float sigm_(float x) {
    x = fminf(fmaxf(x, -30.f), 30.f);
    return 1.f / (1.f + __expf(-x));
}
__device__ __forceinline__ float tanh_(float x) {
    x = fminf(fmaxf(x, -15.f), 15.f);
    float e = __expf(-2.f * x);
    return (1.f - e) / (1.f + e);
}

// 16B system-scope load (LLC-coherent), as two u64 atomic loads.
__device__ __forceinline__ f16x8 ld16_sys(const f16* __restrict__ p) {
    union { u64 w[2]; f16x8 v; } u;
    u.w[0] = __hip_atomic_load((const u64*)p,     __ATOMIC_RELAXED,
                               __HIP_MEMORY_SCOPE_SYSTEM);
    u.w[1] = __hip_atomic_load((const u64*)p + 1, __ATOMIC_RELAXED,
                               __HIP_MEMORY_SCOPE_SYSTEM);
    return u.v;
}

// A-fragment for 16x16x32 f16 MFMA DIRECT from a published global h-plane
// ([16 wg][8 b][32 u] f16). A[m=lane&15][k=(lane>>4)*8+j]; m = batch
// (0..7 valid, 8..15 -> zeros). Fragment = 16 contiguous bytes.
__device__ __forceinline__ f16x8 afrag_gbl(const f16* __restrict__ gp, int kk,
                                           int ln, int q) {
    if (ln < 8) {
        return ld16_sys(gp + kk * 256 + ln * 32 + q * 8);
    }
    f16x8 z = {(_Float16)0, (_Float16)0, (_Float16)0, (_Float16)0,
               (_Float16)0, (_Float16)0, (_Float16)0, (_Float16)0};
    return z;
}

__device__ __forceinline__ f16x8 pack8(const float* p) {
    float4 a = *(const float4*)p, b = *(const float4*)(p + 4);
    f16x8 f;
    f[0] = (f16)a.x; f[1] = (f16)a.y; f[2] = (f16)a.z; f[3] = (f16)a.w;
    f[4] = (f16)b.x; f[5] = (f16)b.y; f[6] = (f16)b.z; f[7] = (f16)b.w;
    return f;
}

// Wait until all 16 flag0 >= t0 AND all 16 flag1 >= t1.
// CALLED BY WAVE 0 ONLY: lanes 0-15 load flag0, 16-31 flag1, 32-63 duplicate;
// single __all vote; relaxed system loads. Graduated backoff caps the poll
// pressure in pathological-skew states (r11's 36-45 ms outliers).
__device__ __forceinline__ void wait_flags(const int* f0, int t0,
                                           const int* f1, int t1, int lane) {
    const int* p = (lane & 16) ? (f1 + (lane & 15)) : (f0 + (lane & 15));
    const int tgt = (lane & 16) ? t1 : t0;
    int spins = 0;
    for (;;) {
        int v = __hip_atomic_load(p, __ATOMIC_RELAXED, __HIP_MEMORY_SCOPE_SYSTEM);
        if (__all(v >= tgt)) break;
        ++spins;
        if (spins < 8)       __builtin_amdgcn_s_sleep(1);
        else if (spins < 64) __builtin_amdgcn_s_sleep(4);
        else                 __builtin_amdgcn_s_sleep(16);
        if (spins > (1 << 20)) break;   // anti-hang safety valve
    }
}

// x A-fragment for step t.
__device__ __forceinline__ f16x8 load_xfrag(const float* __restrict__ x,
                                            int gb8, int t, int ln, int q) {
    f16x8 f = {(_Float16)0, (_Float16)0, (_Float16)0, (_Float16)0,
               (_Float16)0, (_Float16)0, (_Float16)0, (_Float16)0};
    if (ln < 8 && t < T_STEPS) {
        const float* xp = x + ((size_t)(gb8 + ln) * 1024 + t) * 21;
#pragma unroll
        for (int j = 0; j < 8; ++j) {
            int kl = q * 8 + j;
            if (kl < 21) f[j] = (f16)xp[kl];
        }
    }
    return f;
}

// Zeros must be visible at the LLC -> sc0sc1 stores.
__global__ void zero_ws_kernel(unsigned* __restrict__ p, int ndw) {
    int i = blockIdx.x * blockDim.x + threadIdx.x;
    int stride = gridDim.x * blockDim.x;
    for (; i < ndw; i += stride)
        __hip_atomic_store(p + i, 0u, __ATOMIC_RELAXED, __HIP_MEMORY_SCOPE_SYSTEM);
}

__global__ __launch_bounds__(256, 1)
void lstm_persist(const float* __restrict__ x,
                  const float* __restrict__ Wx0, const float* __restrict__ bx0,
                  const float* __restrict__ Wh0,
                  const float* __restrict__ Wx1, const float* __restrict__ bx1,
                  const float* __restrict__ Wh1,
                  const float* __restrict__ Wo,  const float* __restrict__ bo,
                  float* __restrict__ out, char* __restrict__ ws) {
    struct SM {
        float g[4][8][33];                       // gate tiles [gate][b][u0..31]+pad
        float c[8][32];                          // this WG's cell state
        float bias[4][32];                       // this WG's bias slice
        __align__(8)  f16 hout[8][32];           // activation -> packed store
        __align__(16) f16 planeB[8 * HP_STRIDE]; // h1(t-1) mirror for out-proj
        char  pad[84 * 1024];                    // force 1 WG/CU
    };
    __shared__ SM sm;
    const int tid = threadIdx.x;
    if (tid == 0x00FFFFFFu) sm.pad[0] = 1;       // keep pad alive

    const int bid  = blockIdx.x;
    const int g    = bid & 7;        // group (XCD-affine under round-robin)
    const int rk   = bid >> 3;       // 0..31 within group
    const int role = rk >> 4;        // 0: layer-0 WG, 1: layer-1 WG
    const int r    = rk & 15;        // rank within role
    const int w    = tid >> 6;       // wave id = gate type (i,f,g,o)
    const int lane = tid & 63;
    const int ln   = lane & 15;
    const int q    = lane >> 4;
    const int gb8  = g * 8;

    int* barb  = (int*)(ws + WS_FLAG_OFF) + g * 128;  // 512 B per group
    int* flag0 = barb;               // 16 per-L0-WG monotone step flags
    int* flag1 = barb + 64;          // 16 per-L1-WG flags (separate line)
    f16* H0g = (f16*)(ws + WS_H0_OFF) + g * 16384;  // 4 depth planes
    f16* H1g = (f16*)(ws + WS_H1_OFF) + g * 8192;   // 2 depth planes

    // ---- LDS init -------------------------------------------------------
    ((float*)sm.c)[tid] = 0.f;                   // 8*32 = 256 floats
    if (tid < 128) {
        int gate = tid >> 5, u = tid & 31;
        const float* bx = role ? bx1 : bx0;
        sm.bias[gate][u] = bx[(gate << 9) + (r << 5) + u];
    }

    // ---- persistent weight fragments in registers -----------------------
    // W[ ]: role 0 -> W[tau*17+kk] (K=544: Wh0|Wx0pad), tau in {0,1} n-tiles.
    //       role 1 -> W[tau*32+kk] (K=1024: Wx1|Wh1).
    f16x8 W[64];
    if (role == 0) {
#pragma unroll
        for (int tau = 0; tau < 2; ++tau) {
            const int rw = (w << 9) + (r << 5) + tau * 16 + ln;
            const float* wh0r = Wh0 + (size_t)rw * 512;
#pragma unroll
            for (int kk = 0; kk < 16; ++kk)
                W[tau * 17 + kk] = pack8(wh0r + kk * 32 + q * 8);
            const float* wx0r = Wx0 + (size_t)rw * 21;
            f16x8 f = {(_Float16)0, (_Float16)0, (_Float16)0, (_Float16)0,
                       (_Float16)0, (_Float16)0, (_Float16)0, (_Float16)0};
#pragma unroll
            for (int j = 0; j < 8; ++j) {
                int kl = q * 8 + j;
                if (kl < 21) f[j] = (f16)wx0r[kl];
            }
            W[tau * 17 + 16] = f;
        }
    } else {
#pragma unroll
        for (int tau = 0; tau < 2; ++tau) {
            const int rw = (w << 9) + (r << 5) + tau * 16 + ln;
            const float* wx1r = Wx1 + (size_t)rw * 512;
            const float* wh1r = Wh1 + (size_t)rw * 512;
#pragma unroll
            for (int kk = 0; kk < 16; ++kk)
                W[tau * 32 + kk] = pack8(wx1r + kk * 32 + q * 8);
#pragma unroll
            for (int kk = 16; kk < 32; ++kk)
                W[tau * 32 + kk] = pack8(wh1r + (kk - 16) * 32 + q * 8);
        }
    }
    __syncthreads();

    if (role == 0) {
        // =================== layer-0 pipeline stage =======================
        // Writes h0(t) -> plane t&3. Waits flag1 >= t-3 so h0(t-4)'s plane is
        // consumed before overwrite; runs up to 3 steps ahead of L1.
        for (int t = 0; t < T_STEPS; ++t) {
            const int wr = t & 3, rd = (t + 3) & 3;
            f16x8 xf = load_xfrag(x, gb8, t, ln, q);   // prefetch before wait
            if (tid < 64) wait_flags(flag0, t, flag1, t - 3, lane);
            __syncthreads();                           // release waves 1-3

            const f16* hp = H0g + rd * 4096;           // h0(t-1), direct LLC
            f32x4 a0 = {0, 0, 0, 0}, a1 = {0, 0, 0, 0};
#pragma unroll
            for (int half = 0; half < 2; ++half) {
                f16x8 Af[8];
#pragma unroll
                for (int j = 0; j < 8; ++j)
                    Af[j] = afrag_gbl(hp, half * 8 + j, ln, q);
#pragma unroll
                for (int j = 0; j < 8; ++j) {
                    const int kk = half * 8 + j;
                    a0 = __builtin_amdgcn_mfma_f32_16x16x32_f16(Af[j], W[kk], a0, 0, 0, 0);
                    a1 = __builtin_amdgcn_mfma_f32_16x16x32_f16(Af[j], W[17 + kk], a1, 0, 0, 0);
                }
            }
            a0 = __builtin_amdgcn_mfma_f32_16x16x32_f16(xf, W[16], a0, 0, 0, 0);
            a1 = __builtin_amdgcn_mfma_f32_16x16x32_f16(xf, W[33], a1, 0, 0, 0);
            if (q < 2) {
#pragma unroll
                for (int r4 = 0; r4 < 4; ++r4) {
                    sm.g[w][q * 4 + r4][ln] = a0[r4];
                    sm.g[w][q * 4 + r4][16 + ln] = a1[r4];
                }
            }
            __syncthreads();
            {   // activation: 8 batches x 32 units = 256 threads
                int b = tid >> 5, u = tid & 31;
                float gi = sm.g[0][b][u] + sm.bias[0][u];
                float gf = sm.g[1][b][u] + sm.bias[1][u];
                float gg = sm.g[2][b][u] + sm.bias[2][u];
                float go = sm.g[3][b][u] + sm.bias[3][u];
                float iv = sigm_(gi), fv = sigm_(gf), gv = tanh_(gg), ov = sigm_(go);
                float c = sm.c[b][u];
                float cn = fv * c + iv * gv;
                sm.c[b][u] = cn;
                sm.hout[b][u] = (f16)(ov * tanh_(cn));
            }
            __syncthreads();
            if (tid < 64) {   // 512 B contiguous WG slice, wave-0 only
                int b = tid >> 3, j = tid & 7;
                u64 v = *(const u64*)&sm.hout[b][j * 4];
                __hip_atomic_store((u64*)(H0g + wr * 4096 + (r << 8) + (b << 5) + (j << 2)),
                                   v, __ATOMIC_RELAXED, __HIP_MEMORY_SCOPE_SYSTEM);
                asm volatile("s_waitcnt vmcnt(0)" ::: "memory");
                if (tid == 0)
                    __hip_atomic_store(flag0 + r, t + 1, __ATOMIC_RELAXED,
                                       __HIP_MEMORY_SCOPE_SYSTEM);
            }
        }
    } else {
        // =================== layer-1 pipeline stage =======================
        for (int t = 0; t < T_STEPS; ++t) {
            const int wr = t & 1, rd = wr ^ 1;

            // ---- h0(t) half first (L0 runs ahead -> wait usually instant) -
            if (tid < 64) wait_flags(flag0, t + 1, flag1, t - 1000000000, lane);
            __syncthreads();
            const f16* h0p = H0g + (t & 3) * 4096;     // h0(t), direct LLC
            f32x4 a0 = {0, 0, 0, 0}, a1 = {0, 0, 0, 0};
#pragma unroll
            for (int half = 0; half < 2; ++half) {
                f16x8 Af[8];
#pragma unroll
                for (int j = 0; j < 8; ++j)
                    Af[j] = afrag_gbl(h0p, half * 8 + j, ln, q);
#pragma unroll
                for (int j = 0; j < 8; ++j) {
                    const int kk = half * 8 + j;
                    a0 = __builtin_amdgcn_mfma_f32_16x16x32_f16(Af[j], W[kk], a0, 0, 0, 0);
                    a1 = __builtin_amdgcn_mfma_f32_16x16x32_f16(Af[j], W[32 + kk], a1, 0, 0, 0);
                }
            }

            // ---- h1(t-1) half: the self-recurrence crossing ---------------
            if (tid < 64) wait_flags(flag1, t, flag1, t, lane);
            __syncthreads();
            const f16* h1p = H1g + rd * 4096;          // h1(t-1), direct LLC
#pragma unroll
            for (int half = 0; half < 2; ++half) {
                f16x8 Af[8];
#pragma unroll
                for (int j = 0; j < 8; ++j)
                    Af[j] = afrag_gbl(h1p, half * 8 + j, ln, q);
                // LDS mirror for out-proj: written BEFORE flag1=t+1 publish,
                // read after the act barrier -> same no-race ordering as the
                // r8 staged plane (next overwrite is after the next wait's
                // barrier, which orders it after all out-proj reads).
                if (w == 0 && ln < 8) {
#pragma unroll
                    for (int j = 0; j < 8; ++j)
                        *(f16x8*)(sm.planeB + ln * HP_STRIDE +
                                  (half * 8 + j) * 32 + q * 8) = Af[j];
                }
#pragma unroll
                for (int j = 0; j < 8; ++j) {
                    const int kk = 16 + half * 8 + j;
                    a0 = __builtin_amdgcn_mfma_f32_16x16x32_f16(Af[j], W[kk], a0, 0, 0, 0);
                    a1 = __builtin_amdgcn_mfma_f32_16x16x32_f16(Af[j], W[32 + kk], a1, 0, 0, 0);
                }
            }
            if (q < 2) {
#pragma unroll
                for (int r4 = 0; r4 < 4; ++r4) {
                    sm.g[w][q * 4 + r4][ln] = a0[r4];
                    sm.g[w][q * 4 + r4][16 + ln] = a1[r4];
                }
            }
            __syncthreads();
            {
                int b = tid >> 5, u = tid & 31;
                float gi = sm.g[0][b][u] + sm.bias[0][u];
                float gf = sm.g[1][b][u] + sm.bias[1][u];
                float gg = sm.g[2][b][u] + sm.bias[2][u];
                float go = sm.g[3][b][u] + sm.bias[3][u];
                float iv = sigm_(gi), fv = sigm_(gf), gv = tanh_(gg), ov = sigm_(go);
                float c = sm.c[b][u];
                float cn = fv * c + iv * gv;
                sm.c[b][u] = cn;
                sm.hout[b][u] = (f16)(ov * tanh_(cn));
            }
            __syncthreads();
            if (tid < 64) {
                int b = tid >> 3, j = tid & 7;
                u64 v = *(const u64*)&sm.hout[b][j * 4];
                __hip_atomic_store((u64*)(H1g + wr * 4096 + (r << 8) + (b << 5) + (j << 2)),
                                   v, __ATOMIC_RELAXED, __HIP_MEMORY_SCOPE_SYSTEM);
                asm volatile("s_waitcnt vmcnt(0)" ::: "memory");
                if (tid == 0)
                    __hip_atomic_store(flag1 + r, t + 1, __ATOMIC_RELAXED,
                                       __HIP_MEMORY_SCOPE_SYSTEM);
            }

            // ---- out-proj(t-1) AFTER publish, from the LDS mirror (off
            // path). Safe: next mirror write happens after the next wait's
            // __syncthreads, which orders it after these reads.
            if (t > 0) {
                int p = tid >> 4, kp = tid & 15;
                int valid = (p < 10);
                int idx = r * 10 + p;
                int b = valid ? idx / 20 : 0, o = valid ? idx % 20 : 0;
                float a = 0.f;
                if (valid) {
                    const f16* hp = sm.planeB + b * HP_STRIDE + kp * 32;
                    const float* wo = Wo + (size_t)o * 512 + kp * 32;
#pragma unroll
                    for (int k = 0; k < 32; k += 8) {
                        f16x8 hv = *(const f16x8*)(hp + k);
                        float4 wa = *(const float4*)(wo + k);
                        float4 wb = *(const float4*)(wo + k + 4);
                        a += (float)hv[0] * wa.x + (float)hv[1] * wa.y +
                             (float)hv[2] * wa.z + (float)hv[3] * wa.w +
                             (float)hv[4] * wb.x + (float)hv[5] * wb.y +
                             (float)hv[6] * wb.z + (float)hv[7] * wb.w;
                    }
                }
                a += __shfl_down(a, 8, 16);
                a += __shfl_down(a, 4, 16);
                a += __shfl_down(a, 2, 16);
                a += __shfl_down(a, 1, 16);
                if (valid && kp == 0)
                    out[((size_t)(gb8 + b) * 1024 + (t - 1)) * 20 + o] =
                        sigm_(a + bo[o]);
            }
        }

        // ===== epilogue: out(T-1) from h1(T-1), direct from global ========
        // Safe without a mirror: after flag1 >= T there are no more writers
        // of the h1 planes, so the LLC copy is final.
        if (tid < 64) wait_flags(flag1, T_STEPS, flag1, T_STEPS, lane);
        __syncthreads();
        const f16* h1p = H1g + ((T_STEPS - 1) & 1) * 4096;
        {
            int p = tid >> 4, kp = tid & 15;
            int valid = (p < 10);
            int idx = r * 10 + p;
            int b = valid ? idx / 20 : 0, o = valid ? idx % 20 : 0;
            float a = 0.f;
            if (valid) {
                const f16* hp = h1p + kp * 256 + b * 32;
                const float* wo = Wo + (size_t)o * 512 + kp * 32;
#pragma unroll
                for (int k = 0; k < 32; k += 8) {
                    f16x8 hv = ld16_sys(hp + k);
                    float4 wa = *(const float4*)(wo + k);
                    float4 wb = *(const float4*)(wo + k + 4);
                    a += (float)hv[0] * wa.x + (float)hv[1] * wa.y +
                         (float)hv[2] * wa.z + (float)hv[3] * wa.w +
                         (float)hv[4] * wb.x + (float)hv[5] * wb.y +
                         (float)hv[6] * wb.z + (float)hv[7] * wb.w;
                }
            }
            a += __shfl_down(a, 8, 16);
            a += __shfl_down(a, 4, 16);
            a += __shfl_down(a, 2, 16);
            a += __shfl_down(a, 1, 16);
            if (valid && kp == 0)
                out[((size_t)(gb8 + b) * 1024 + (T_STEPS - 1)) * 20 + o] =
                    sigm_(a + bo[o]);
        }
    }
}

extern "C" void kernel_launch(void* const* d_in, const int* in_sizes, int n_in,
                              void* d_out, int out_size, void* d_ws, size_t ws_size,
                              hipStream_t stream) {
    const float* x   = (const float*)d_in[0];
    const float* Wx0 = (const float*)d_in[1];
    const float* bx0 = (const float*)d_in[2];
    const float* Wh0 = (const float*)d_in[3];
    const float* Wx1 = (const float*)d_in[4];
    const float* bx1 = (const float*)d_in[5];
    const float* Wh1 = (const float*)d_in[6];
    const float* Wo  = (const float*)d_in[7];
    const float* bo  = (const float*)d_in[8];
    float* out = (float*)d_out;
    char*  ws  = (char*)d_ws;

    if (ws_size < (size_t)WS_NEED) return;   // fail visibly (out stays poisoned)

    zero_ws_kernel<<<128, 256, 0, stream>>>((unsigned*)ws, WS_NEED / 4);
    lstm_persist<<<256, 256, 0, stream>>>(x, Wx0, bx0, Wh0, Wx1, bx1, Wh1,
                                          Wo, bo, out, ws);
}

// Round 2
// 4670.824 us; speedup vs baseline: 1.4152x; 1.4152x over previous
//
#include <hip/hip_runtime.h>

// ---------------------------------------------------------------------------
// Persistent 2-layer LSTM, MI355X. Round 13 = Round-11 proven base (4850 us)
// + MERGED L1 WAIT/STAGE + poll backoff. r12 post-mortem: direct-LLC
// A-fragments removed staging (bank-conflicts 9.9e7->2.4e7 as predicted) but
// cost 4 sequential system-scope load round-trips per L1 step -> +1.75us/step.
// REVERTED. This round keeps cooperative LDS staging (1x traffic, parallel)
// and instead merges L1's two waits + two stagings into ONE: wait(flag0>=t+1
// && flag1>=t) up front (both normally satisfied: L0 runs 3 ahead; peers'
// flag1 lands during our out-proj), then stage planeA+planeB in a single
// 8-load pass -> one LLC round-trip instead of two, and 2 fewer barriers per
// L1 step. Everything else r8/r11 verbatim: 16 L0-WGs + 16 L1-WGs per group,
// weights in VGPRs, h0 depth-4 / h1 depth-2 planes, relaxed system-scope LLC
// ops, per-WG monotone flags, wave-0-only polling, 1 WG/CU pad.
// ---------------------------------------------------------------------------

#define T_STEPS 1024
#define WS_FLAG_OFF 0                     // 8 groups * 128 ints (512 B apart)
#define WS_H0_OFF  4096                   // [8 g][4 depth][16 wg][8 b][32 u] f16
#define WS_H1_OFF  (4096 + 8*4*8192)      // [8 g][2 depth][...]
#define WS_NEED    (WS_H1_OFF + 8*2*8192) // 397312 B (known-good size)

typedef _Float16 f16;
typedef _Float16 f16x8 __attribute__((ext_vector_type(8)));
typedef float    f32x4 __attribute__((ext_vector_type(4)));
typedef unsigned long long u64;

#define HP_STRIDE 520   // padded LDS plane row stride (f16)

__device__ __forceinline__ float sigm_(float x) {
    x = fminf(fmaxf(x, -30.f), 30.f);
    return 1.f / (1.f + __expf(-x));
}
__device__ __forceinline__ float tanh_(float x) {
    x = fminf(fmaxf(x, -15.f), 15.f);
    float e = __expf(-2.f * x);
    return (1.f - e) / (1.f + e);
}

// A-fragment for 16x16x32 f16 MFMA from a padded LDS plane.
// A[m=lane&15][k=(lane>>4)*8+j]; m = batch (0..7 valid, 8..15 -> zeros).
__device__ __forceinline__ f16x8 afrag_lds(const f16* __restrict__ hp, int kbase,
                                           int b, int q) {
    if (b < 8) {
        return *(const f16x8*)(hp + b * HP_STRIDE + kbase + q * 8);
    }
    f16x8 z = {(_Float16)0, (_Float16)0, (_Float16)0, (_Float16)0,
               (_Float16)0, (_Float16)0, (_Float16)0, (_Float16)0};
    return z;
}

__device__ __forceinline__ f16x8 pack8(const float* p) {
    float4 a = *(const float4*)p, b = *(const float4*)(p + 4);
    f16x8 f;
    f[0] = (f16)a.x; f[1] = (f16)a.y; f[2] = (f16)a.z; f[3] = (f16)a.w;
    f[4] = (f16)b.x; f[5] = (f16)b.y; f[6] = (f16)b.z; f[7] = (f16)b.w;
    return f;
}

// Wait until all 16 flag0 >= t0 AND all 16 flag1 >= t1.
// CALLED BY WAVE 0 ONLY: lanes 0-15 load flag0, 16-31 flag1, 32-63 duplicate;
// single __all vote; relaxed system loads. Graduated backoff caps poll
// pressure in pathological-skew states (the rare 36-48 ms outliers).
__device__ __forceinline__ void wait_flags(const int* f0, int t0,
                                           const int* f1, int t1, int lane) {
    const int* p = (lane & 16) ? (f1 + (lane & 15)) : (f0 + (lane & 15));
    const int tgt = (lane & 16) ? t1 : t0;
    int spins = 0;
    for (;;) {
        int v = __hip_atomic_load(p, __ATOMIC_RELAXED, __HIP_MEMORY_SCOPE_SYSTEM);
        if (__all(v >= tgt)) break;
        ++spins;
        if (spins < 8)       __builtin_amdgcn_s_sleep(1);
        else if (spins < 64) __builtin_amdgcn_s_sleep(4);
        else                 __builtin_amdgcn_s_sleep(16);
        if (spins > (1 << 20)) break;   // anti-hang safety valve
    }
}

// Stage one 8 KB h-plane ([16 wg][8 b][32 u] f16, WG-major global) into the
// padded LDS [batch][unit 0..511] plane. u64 i: wg=i>>6, b=(i>>3)&7, j=i&7.
__device__ __forceinline__ void stage_plane(const f16* __restrict__ gp,
                                            f16* __restrict__ dst, int tid) {
    const u64* g8 = (const u64*)gp;
    u64 v[4];
#pragma unroll
    for (int jj = 0; jj < 4; ++jj)
        v[jj] = __hip_atomic_load(g8 + jj * 256 + tid, __ATOMIC_RELAXED,
                                  __HIP_MEMORY_SCOPE_SYSTEM);
#pragma unroll
    for (int jj = 0; jj < 4; ++jj) {
        int i = jj * 256 + tid;
        int wg = i >> 6, b = (i >> 3) & 7, j = i & 7;
        *(u64*)(dst + b * HP_STRIDE + wg * 32 + j * 4) = v[jj];
    }
}

// Stage TWO 8 KB h-planes in one pass: all 8 global loads issued together
// (single LLC round-trip on the serial chain), then all 8 LDS writes.
__device__ __forceinline__ void stage_two(const f16* __restrict__ gpA,
                                          f16* __restrict__ dstA,
                                          const f16* __restrict__ gpB,
                                          f16* __restrict__ dstB, int tid) {
    const u64* ga = (const u64*)gpA;
    const u64* gb = (const u64*)gpB;
    u64 va[4], vb[4];
#pragma unroll
    for (int jj = 0; jj < 4; ++jj)
        va[jj] = __hip_atomic_load(ga + jj * 256 + tid, __ATOMIC_RELAXED,
                                   __HIP_MEMORY_SCOPE_SYSTEM);
#pragma unroll
    for (int jj = 0; jj < 4; ++jj)
        vb[jj] = __hip_atomic_load(gb + jj * 256 + tid, __ATOMIC_RELAXED,
                                   __HIP_MEMORY_SCOPE_SYSTEM);
#pragma unroll
    for (int jj = 0; jj < 4; ++jj) {
        int i = jj * 256 + tid;
        int wg = i >> 6, b = (i >> 3) & 7, j = i & 7;
        *(u64*)(dstA + b * HP_STRIDE + wg * 32 + j * 4) = va[jj];
        *(u64*)(dstB + b * HP_STRIDE + wg * 32 + j * 4) = vb[jj];
    }
}

// x A-fragment for step t.
__device__ __forceinline__ f16x8 load_xfrag(const float* __restrict__ x,
                                            int gb8, int t, int ln, int q) {
    f16x8 f = {(_Float16)0, (_Float16)0, (_Float16)0, (_Float16)0,
               (_Float16)0, (_Float16)0, (_Float16)0, (_Float16)0};
    if (ln < 8 && t < T_STEPS) {
        const float* xp = x + ((size_t)(gb8 + ln) * 1024 + t) * 21;
#pragma unroll
        for (int j = 0; j < 8; ++j) {
            int kl = q * 8 + j;
            if (kl < 21) f[j] = (f16)xp[kl];
        }
    }
    return f;
}

// Zeros must be visible at the LLC -> system-scope stores.
__global__ void zero_ws_kernel(unsigned* __restrict__ p, int ndw) {
    int i = blockIdx.x * blockDim.x + threadIdx.x;
    int stride = gridDim.x * blockDim.x;
    for (; i < ndw; i += stride)
        __hip_atomic_store(p + i, 0u, __ATOMIC_RELAXED, __HIP_MEMORY_SCOPE_SYSTEM);
}

__global__ __launch_bounds__(256, 1)
void lstm_persist(const float* __restrict__ x,
                  const float* __restrict__ Wx0, const float* __restrict__ bx0,
                  const float* __restrict__ Wh0,
                  const float* __restrict__ Wx1, const float* __restrict__ bx1,
                  const float* __restrict__ Wh1,
                  const float* __restrict__ Wo,  const float* __restrict__ bo,
                  float* __restrict__ out, char* __restrict__ ws) {
    struct SM {
        float g[4][8][33];                       // gate tiles [gate][b][u0..31]+pad
        float c[8][32];                          // this WG's cell state
        float bias[4][32];                       // this WG's bias slice
        __align__(8)  f16 hout[8][32];           // activation -> packed store
        __align__(16) f16 planeA[8 * HP_STRIDE]; // h0 plane
        __align__(16) f16 planeB[8 * HP_STRIDE]; // h1 plane (L1 only)
        char  pad[60 * 1024];                    // force 1 WG/CU
    };
    __shared__ SM sm;
    const int tid = threadIdx.x;
    if (tid == 0x00FFFFFFu) sm.pad[0] = 1;       // keep pad alive

    const int bid  = blockIdx.x;
    const int g    = bid & 7;        // group (XCD-affine under round-robin)
    const int rk   = bid >> 3;       // 0..31 within group
    const int role = rk >> 4;        // 0: layer-0 WG, 1: layer-1 WG
    const int r    = rk & 15;        // rank within role
    const int w    = tid >> 6;       // wave id = gate type (i,f,g,o)
    const int lane = tid & 63;
    const int ln   = lane & 15;
    const int q    = lane >> 4;
    const int gb8  = g * 8;

    int* barb  = (int*)(ws + WS_FLAG_OFF) + g * 128;  // 512 B per group
    int* flag0 = barb;               // 16 per-L0-WG monotone step flags
    int* flag1 = barb + 64;          // 16 per-L1-WG flags (separate line)
    f16* H0g = (f16*)(ws + WS_H0_OFF) + g * 16384;  // 4 depth planes
    f16* H1g = (f16*)(ws + WS_H1_OFF) + g * 8192;   // 2 depth planes

    // ---- LDS init -------------------------------------------------------
    ((float*)sm.c)[tid] = 0.f;                   // 8*32 = 256 floats
    if (tid < 128) {
        int gate = tid >> 5, u = tid & 31;
        const float* bx = role ? bx1 : bx0;
        sm.bias[gate][u] = bx[(gate << 9) + (r << 5) + u];
    }

    // ---- persistent weight fragments in registers -----------------------
    // W[ ]: role 0 -> W[tau*17+kk] (K=544: Wh0|Wx0pad), tau in {0,1} n-tiles.
    //       role 1 -> W[tau*32+kk] (K=1024: Wx1|Wh1).
    f16x8 W[64];
    if (role == 0) {
#pragma unroll
        for (int tau = 0; tau < 2; ++tau) {
            const int rw = (w << 9) + (r << 5) + tau * 16 + ln;
            const float* wh0r = Wh0 + (size_t)rw * 512;
#pragma unroll
            for (int kk = 0; kk < 16; ++kk)
                W[tau * 17 + kk] = pack8(wh0r + kk * 32 + q * 8);
            const float* wx0r = Wx0 + (size_t)rw * 21;
            f16x8 f = {(_Float16)0, (_Float16)0, (_Float16)0, (_Float16)0,
                       (_Float16)0, (_Float16)0, (_Float16)0, (_Float16)0};
#pragma unroll
            for (int j = 0; j < 8; ++j) {
                int kl = q * 8 + j;
                if (kl < 21) f[j] = (f16)wx0r[kl];
            }
            W[tau * 17 + 16] = f;
        }
    } else {
#pragma unroll
        for (int tau = 0; tau < 2; ++tau) {
            const int rw = (w << 9) + (r << 5) + tau * 16 + ln;
            const float* wx1r = Wx1 + (size_t)rw * 512;
            const float* wh1r = Wh1 + (size_t)rw * 512;
#pragma unroll
            for (int kk = 0; kk < 16; ++kk)
                W[tau * 32 + kk] = pack8(wx1r + kk * 32 + q * 8);
#pragma unroll
            for (int kk = 16; kk < 32; ++kk)
                W[tau * 32 + kk] = pack8(wh1r + (kk - 16) * 32 + q * 8);
        }
    }
    __syncthreads();

    if (role == 0) {
        // =================== layer-0 pipeline stage =======================
        // Writes h0(t) -> plane t&3. Waits flag1 >= t-3 so h0(t-4)'s plane is
        // consumed before overwrite; runs up to 3 steps ahead of L1.
        for (int t = 0; t < T_STEPS; ++t) {
            const int wr = t & 3, rd = (t + 3) & 3;
            f16x8 xf = load_xfrag(x, gb8, t, ln, q);   // prefetch before wait
            if (tid < 64) wait_flags(flag0, t, flag1, t - 3, lane);
            __syncthreads();                           // release waves 1-3
            stage_plane(H0g + rd * 4096, sm.planeA, tid);
            __syncthreads();

            f32x4 a0 = {0, 0, 0, 0}, a1 = {0, 0, 0, 0};
#pragma unroll
            for (int kk = 0; kk < 16; ++kk) {
                f16x8 A = afrag_lds(sm.planeA, kk * 32, ln, q);
                a0 = __builtin_amdgcn_mfma_f32_16x16x32_f16(A, W[kk], a0, 0, 0, 0);
                a1 = __builtin_amdgcn_mfma_f32_16x16x32_f16(A, W[17 + kk], a1, 0, 0, 0);
            }
            a0 = __builtin_amdgcn_mfma_f32_16x16x32_f16(xf, W[16], a0, 0, 0, 0);
            a1 = __builtin_amdgcn_mfma_f32_16x16x32_f16(xf, W[33], a1, 0, 0, 0);
            if (q < 2) {
#pragma unroll
                for (int r4 = 0; r4 < 4; ++r4) {
                    sm.g[w][q * 4 + r4][ln] = a0[r4];
                    sm.g[w][q * 4 + r4][16 + ln] = a1[r4];
                }
            }
            __syncthreads();
            {   // activation: 8 batches x 32 units = 256 threads
                int b = tid >> 5, u = tid & 31;
                float gi = sm.g[0][b][u] + sm.bias[0][u];
                float gf = sm.g[1][b][u] + sm.bias[1][u];
                float gg = sm.g[2][b][u] + sm.bias[2][u];
                float go = sm.g[3][b][u] + sm.bias[3][u];
                float iv = sigm_(gi), fv = sigm_(gf), gv = tanh_(gg), ov = sigm_(go);
                float c = sm.c[b][u];
                float cn = fv * c + iv * gv;
                sm.c[b][u] = cn;
                sm.hout[b][u] = (f16)(ov * tanh_(cn));
            }
            __syncthreads();
            if (tid < 64) {   // 512 B contiguous WG slice, wave-0 only
                int b = tid >> 3, j = tid & 7;
                u64 v = *(const u64*)&sm.hout[b][j * 4];
                __hip_atomic_store((u64*)(H0g + wr * 4096 + (r << 8) + (b << 5) + (j << 2)),
                                   v, __ATOMIC_RELAXED, __HIP_MEMORY_SCOPE_SYSTEM);
                asm volatile("s_waitcnt vmcnt(0)" ::: "memory");
                if (tid == 0)
                    __hip_atomic_store(flag0 + r, t + 1, __ATOMIC_RELAXED,
                                       __HIP_MEMORY_SCOPE_SYSTEM);
            }
        }
    } else {
        // =================== layer-1 pipeline stage =======================
        // MERGED: one wait (flag0>=t+1 && flag1>=t), one dual-plane staging
        // pass, then all 64 MFMAs. Saves one LLC round-trip + 2 barriers per
        // step vs the split structure. Both flags are normally satisfied at
        // entry: L0 runs up to 3 ahead; peers' flag1 stores land while this
        // WG runs out-proj(t-1) at the tail of the previous iteration.
        for (int t = 0; t < T_STEPS; ++t) {
            const int wr = t & 1, rd = wr ^ 1;

            if (tid < 64) wait_flags(flag0, t + 1, flag1, t, lane);
            __syncthreads();
            stage_two(H0g + (t & 3) * 4096, sm.planeA,   // h0(t)
                      H1g + rd * 4096,      sm.planeB,   // h1(t-1)
                      tid);
            __syncthreads();

            f32x4 a0 = {0, 0, 0, 0}, a1 = {0, 0, 0, 0};
#pragma unroll
            for (int kk = 0; kk < 16; ++kk) {
                f16x8 A = afrag_lds(sm.planeA, kk * 32, ln, q);
                a0 = __builtin_amdgcn_mfma_f32_16x16x32_f16(A, W[kk], a0, 0, 0, 0);
                a1 = __builtin_amdgcn_mfma_f32_16x16x32_f16(A, W[32 + kk], a1, 0, 0, 0);
            }
#pragma unroll
            for (int kk = 16; kk < 32; ++kk) {
                f16x8 A = afrag_lds(sm.planeB, (kk - 16) * 32, ln, q);
                a0 = __builtin_amdgcn_mfma_f32_16x16x32_f16(A, W[kk], a0, 0, 0, 0);
                a1 = __builtin_amdgcn_mfma_f32_16x16x32_f16(A, W[32 + kk], a1, 0, 0, 0);
            }
            if (q < 2) {
#pragma unroll
                for (int r4 = 0; r4 < 4; ++r4) {
                    sm.g[w][q * 4 + r4][ln] = a0[r4];
                    sm.g[w][q * 4 + r4][16 + ln] = a1[r4];
                }
            }
            __syncthreads();
            {
                int b = tid >> 5, u = tid & 31;
                float gi = sm.g[0][b][u] + sm.bias[0][u];
                float gf = sm.g[1][b][u] + sm.bias[1][u];
                float gg = sm.g[2][b][u] + sm.bias[2][u];
                float go = sm.g[3][b][u] + sm.bias[3][u];
                float iv = sigm_(gi), fv = sigm_(gf), gv = tanh_(gg), ov = sigm_(go);
                float c = sm.c[b][u];
                float cn = fv * c + iv * gv;
                sm.c[b][u] = cn;
                sm.hout[b][u] = (f16)(ov * tanh_(cn));
            }
            __syncthreads();
            if (tid < 64) {
                int b = tid >> 3, j = tid & 7;
                u64 v = *(const u64*)&sm.hout[b][j * 4];
                __hip_atomic_store((u64*)(H1g + wr * 4096 + (r << 8) + (b << 5) + (j << 2)),
                                   v, __ATOMIC_RELAXED, __HIP_MEMORY_SCOPE_SYSTEM);
                asm volatile("s_waitcnt vmcnt(0)" ::: "memory");
                if (tid == 0)
                    __hip_atomic_store(flag1 + r, t + 1, __ATOMIC_RELAXED,
                                       __HIP_MEMORY_SCOPE_SYSTEM);
            }

            // ---- out-proj(t-1) AFTER publish, from LDS planeB (off the
            // inter-WG path; also hides peers' flag1 crossing for step t+1).
            // Safe: planeB's next overwrite is after the next wait's
            // __syncthreads, which orders it after these reads.
            if (t > 0) {
                int p = tid >> 4, kp = tid & 15;
                int valid = (p < 10);
                int idx = r * 10 + p;
                int b = valid ? idx / 20 : 0, o = valid ? idx % 20 : 0;
                float a = 0.f;
                if (valid) {
                    const f16* hp = sm.planeB + b * HP_STRIDE + kp * 32;
                    const float* wo = Wo + (size_t)o * 512 + kp * 32;
#pragma unroll
                    for (int k = 0; k < 32; k += 8) {
                        f16x8 hv = *(const f16x8*)(hp + k);
                        float4 wa = *(const float4*)(wo + k);
                        float4 wb = *(const float4*)(wo + k + 4);
                        a += (float)hv[0] * wa.x + (float)hv[1] * wa.y +
                             (float)hv[2] * wa.z + (float)hv[3] * wa.w +
                             (float)hv[4] * wb.x + (float)hv[5] * wb.y +
                             (float)hv[6] * wb.z + (float)hv[7] * wb.w;
                    }
                }
                a += __shfl_down(a, 8, 16);
                a += __shfl_down(a, 4, 16);
                a += __shfl_down(a, 2, 16);
                a += __shfl_down(a, 1, 16);
                if (valid && kp == 0)
                    out[((size_t)(gb8 + b) * 1024 + (t - 1)) * 20 + o] =
                        sigm_(a + bo[o]);
            }
        }

        // ===== epilogue: out(T-1) from h1(T-1) =============================
        if (tid < 64) wait_flags(flag1, T_STEPS, flag1, T_STEPS, lane);
        __syncthreads();
        stage_plane(H1g + ((T_STEPS - 1) & 1) * 4096, sm.planeB, tid);
        __syncthreads();
        {
            int p = tid >> 4, kp = tid & 15;
            int valid = (p < 10);
            int idx = r * 10 + p;
            int b = valid ? idx / 20 : 0, o = valid ? idx % 20 : 0;
            float a = 0.f;
            if (valid) {
                const f16* hp = sm.planeB + b * HP_STRIDE + kp * 32;
                const float* wo = Wo + (size_t)o * 512 + kp * 32;
#pragma unroll
                for (int k = 0; k < 32; k += 8) {
                    f16x8 hv = *(const f16x8*)(hp + k);
                    float4 wa = *(const float4*)(wo + k);
                    float4 wb = *(const float4*)(wo + k + 4);
                    a += (float)hv[0] * wa.x + (float)hv[1] * wa.y +
                         (float)hv[2] * wa.z + (float)hv[3] * wa.w +
                         (float)hv[4] * wb.x + (float)hv[5] * wb.y +
                         (float)hv[6] * wb.z + (float)hv[7] * wb.w;
                }
            }
            a += __shfl_down(a, 8, 16);
            a += __shfl_down(a, 4, 16);
            a += __shfl_down(a, 2, 16);
            a += __shfl_down(a, 1, 16);
            if (valid && kp == 0)
                out[((size_t)(gb8 + b) * 1024 + (T_STEPS - 1)) * 20 + o] =
                    sigm_(a + bo[o]);
        }
    }
}

extern "C" void kernel_launch(void* const* d_in, const int* in_sizes, int n_in,
                              void* d_out, int out_size, void* d_ws, size_t ws_size,
                              hipStream_t stream) {
    const float* x   = (const float*)d_in[0];
    const float* Wx0 = (const float*)d_in[1];
    const float* bx0 = (const float*)d_in[2];
    const float* Wh0 = (const float*)d_in[3];
    const float* Wx1 = (const float*)d_in[4];
    const float* bx1 = (const float*)d_in[5];
    const float* Wh1 = (const float*)d_in[6];
    const float* Wo  = (const float*)d_in[7];
    const float* bo  = (const float*)d_in[8];
    float* out = (float*)d_out;
    char*  ws  = (char*)d_ws;

    if (ws_size < (size_t)WS_NEED) return;   // fail visibly (out stays poisoned)

    zero_ws_kernel<<<128, 256, 0, stream>>>((unsigned*)ws, WS_NEED / 4);
    lstm_persist<<<256, 256, 0, stream>>>(x, Wx0, bx0, Wh0, Wx1, bx1, Wh1,
                                          Wo, bo, out, ws);
}

// Round 4
// 4615.588 us; speedup vs baseline: 1.4321x; 1.0120x over previous
//
#include <hip/hip_runtime.h>

// ---------------------------------------------------------------------------
// Persistent 2-layer LSTM, MI355X. Round 15 = Round-14 (compile-fixed):
// POLL-PRESSURE HALVING + ADAPTIVE PREDICTIVE SLEEP on the r13 base (4670us).
// r13 post-mortem: L0's loop (~4.67us/step) sets the period; model says its
// intrinsic latency is ~2.3us -> the rest is contention/jitter. Proven lever
// (r11): poll pressure on the two flag lines per group. This round: (1) poll
// lanes 32-63 no longer issue loads (INT_MAX into the __all vote) -> half the
// line requests per poll; (2) each wait site keeps an EWMA of its blocked
// duration (s_memtime) and coarse-sleeps ~half of it (loop of constant
// s_sleep(31) bursts — builtin requires a literal) before fine-polling at
// 64cy quanta -> fewer polls per wait AND tighter detect quantization.
// Escalation retained as outlier protection. Everything else r13 verbatim:
// 16 L0-WGs + 16 L1-WGs per group, weights in VGPRs, h0 depth-4 / h1 depth-2
// planes, merged L1 wait+dual-stage, relaxed system-scope LLC ops, per-WG
// monotone flags, wave-0-only polling, 1 WG/CU pad.
// ---------------------------------------------------------------------------

#define T_STEPS 1024
#define WS_FLAG_OFF 0                     // 8 groups * 128 ints (512 B apart)
#define WS_H0_OFF  4096                   // [8 g][4 depth][16 wg][8 b][32 u] f16
#define WS_H1_OFF  (4096 + 8*4*8192)      // [8 g][2 depth][...]
#define WS_NEED    (WS_H1_OFF + 8*2*8192) // 397312 B (known-good size)

typedef _Float16 f16;
typedef _Float16 f16x8 __attribute__((ext_vector_type(8)));
typedef float    f32x4 __attribute__((ext_vector_type(4)));
typedef unsigned long long u64;

#define HP_STRIDE 520   // padded LDS plane row stride (f16)

__device__ __forceinline__ float sigm_(float x) {
    x = fminf(fmaxf(x, -30.f), 30.f);
    return 1.f / (1.f + __expf(-x));
}
__device__ __forceinline__ float tanh_(float x) {
    x = fminf(fmaxf(x, -15.f), 15.f);
    float e = __expf(-2.f * x);
    return (1.f - e) / (1.f + e);
}

// A-fragment for 16x16x32 f16 MFMA from a padded LDS plane.
// A[m=lane&15][k=(lane>>4)*8+j]; m = batch (0..7 valid, 8..15 -> zeros).
__device__ __forceinline__ f16x8 afrag_lds(const f16* __restrict__ hp, int kbase,
                                           int b, int q) {
    if (b < 8) {
        return *(const f16x8*)(hp + b * HP_STRIDE + kbase + q * 8);
    }
    f16x8 z = {(_Float16)0, (_Float16)0, (_Float16)0, (_Float16)0,
               (_Float16)0, (_Float16)0, (_Float16)0, (_Float16)0};
    return z;
}

__device__ __forceinline__ f16x8 pack8(const float* p) {
    float4 a = *(const float4*)p, b = *(const float4*)(p + 4);
    f16x8 f;
    f[0] = (f16)a.x; f[1] = (f16)a.y; f[2] = (f16)a.z; f[3] = (f16)a.w;
    f[4] = (f16)b.x; f[5] = (f16)b.y; f[6] = (f16)b.z; f[7] = (f16)b.w;
    return f;
}

// Wait until all 16 flag0 >= t0 AND all 16 flag1 >= t1.
// CALLED BY WAVE 0 ONLY. Lanes 0-15 load flag0, 16-31 load flag1, lanes
// 32-63 contribute INT_MAX (NO load -> half the flag-line requests).
// predict_clk: EWMA of this site's recent blocked durations (shader clocks);
// when the first check fails, coarse-sleep ~half of it (constant s_sleep(31)
// bursts, ~2000cy each), then fine-poll at 64cy quanta. Returns blocked
// duration (0 if fast path).
__device__ __forceinline__ long long wait_flags(const int* f0, int t0,
                                                const int* f1, int t1, int lane,
                                                long long predict_clk) {
    const int* p = (lane & 16) ? (f1 + (lane & 15)) : (f0 + (lane & 15));
    const int tgt = (lane & 16) ? t1 : t0;
    const bool act = (lane < 32);
    int v = act ? __hip_atomic_load(p, __ATOMIC_RELAXED, __HIP_MEMORY_SCOPE_SYSTEM)
                : 0x7fffffff;
    if (__all(v >= tgt)) return 0;                 // fast path: no wait
    long long t0c = (long long)__builtin_amdgcn_s_memtime();
    int rep = (int)(predict_clk >> 12);            // ~half wait / ~2000cy burst
    if (rep > 8) rep = 8;
    for (int i = 0; i < rep; ++i) __builtin_amdgcn_s_sleep(31);
    int spins = 0;
    for (;;) {
        v = act ? __hip_atomic_load(p, __ATOMIC_RELAXED, __HIP_MEMORY_SCOPE_SYSTEM)
                : 0x7fffffff;
        if (__all(v >= tgt)) break;
        ++spins;
        if (spins < 32)       __builtin_amdgcn_s_sleep(1);
        else if (spins < 256) __builtin_amdgcn_s_sleep(4);
        else                  __builtin_amdgcn_s_sleep(16);
        if (spins > (1 << 20)) break;   // anti-hang safety valve
    }
    return (long long)__builtin_amdgcn_s_memtime() - t0c;
}

// EWMA update: decay toward the new sample (or toward 0 on fast path).
__device__ __forceinline__ long long ewma_upd(long long ew, long long d) {
    return ew - (ew >> 2) + (d >> 2);
}

// Stage one 8 KB h-plane ([16 wg][8 b][32 u] f16, WG-major global) into the
// padded LDS [batch][unit 0..511] plane. u64 i: wg=i>>6, b=(i>>3)&7, j=i&7.
__device__ __forceinline__ void stage_plane(const f16* __restrict__ gp,
                                            f16* __restrict__ dst, int tid) {
    const u64* g8 = (const u64*)gp;
    u64 v[4];
#pragma unroll
    for (int jj = 0; jj < 4; ++jj)
        v[jj] = __hip_atomic_load(g8 + jj * 256 + tid, __ATOMIC_RELAXED,
                                  __HIP_MEMORY_SCOPE_SYSTEM);
#pragma unroll
    for (int jj = 0; jj < 4; ++jj) {
        int i = jj * 256 + tid;
        int wg = i >> 6, b = (i >> 3) & 7, j = i & 7;
        *(u64*)(dst + b * HP_STRIDE + wg * 32 + j * 4) = v[jj];
    }
}

// Stage TWO 8 KB h-planes in one pass: all 8 global loads issued together
// (single LLC round-trip on the serial chain), then all 8 LDS writes.
__device__ __forceinline__ void stage_two(const f16* __restrict__ gpA,
                                          f16* __restrict__ dstA,
                                          const f16* __restrict__ gpB,
                                          f16* __restrict__ dstB, int tid) {
    const u64* ga = (const u64*)gpA;
    const u64* gb = (const u64*)gpB;
    u64 va[4], vb[4];
#pragma unroll
    for (int jj = 0; jj < 4; ++jj)
        va[jj] = __hip_atomic_load(ga + jj * 256 + tid, __ATOMIC_RELAXED,
                                   __HIP_MEMORY_SCOPE_SYSTEM);
#pragma unroll
    for (int jj = 0; jj < 4; ++jj)
        vb[jj] = __hip_atomic_load(gb + jj * 256 + tid, __ATOMIC_RELAXED,
                                   __HIP_MEMORY_SCOPE_SYSTEM);
#pragma unroll
    for (int jj = 0; jj < 4; ++jj) {
        int i = jj * 256 + tid;
        int wg = i >> 6, b = (i >> 3) & 7, j = i & 7;
        *(u64*)(dstA + b * HP_STRIDE + wg * 32 + j * 4) = va[jj];
        *(u64*)(dstB + b * HP_STRIDE + wg * 32 + j * 4) = vb[jj];
    }
}

// x A-fragment for step t.
__device__ __forceinline__ f16x8 load_xfrag(const float* __restrict__ x,
                                            int gb8, int t, int ln, int q) {
    f16x8 f = {(_Float16)0, (_Float16)0, (_Float16)0, (_Float16)0,
               (_Float16)0, (_Float16)0, (_Float16)0, (_Float16)0};
    if (ln < 8 && t < T_STEPS) {
        const float* xp = x + ((size_t)(gb8 + ln) * 1024 + t) * 21;
#pragma unroll
        for (int j = 0; j < 8; ++j) {
            int kl = q * 8 + j;
            if (kl < 21) f[j] = (f16)xp[kl];
        }
    }
    return f;
}

// Zeros must be visible at the LLC -> system-scope stores.
__global__ void zero_ws_kernel(unsigned* __restrict__ p, int ndw) {
    int i = blockIdx.x * blockDim.x + threadIdx.x;
    int stride = gridDim.x * blockDim.x;
    for (; i < ndw; i += stride)
        __hip_atomic_store(p + i, 0u, __ATOMIC_RELAXED, __HIP_MEMORY_SCOPE_SYSTEM);
}

__global__ __launch_bounds__(256, 1)
void lstm_persist(const float* __restrict__ x,
                  const float* __restrict__ Wx0, const float* __restrict__ bx0,
                  const float* __restrict__ Wh0,
                  const float* __restrict__ Wx1, const float* __restrict__ bx1,
                  const float* __restrict__ Wh1,
                  const float* __restrict__ Wo,  const float* __restrict__ bo,
                  float* __restrict__ out, char* __restrict__ ws) {
    struct SM {
        float g[4][8][33];                       // gate tiles [gate][b][u0..31]+pad
        float c[8][32];                          // this WG's cell state
        float bias[4][32];                       // this WG's bias slice
        __align__(8)  f16 hout[8][32];           // activation -> packed store
        __align__(16) f16 planeA[8 * HP_STRIDE]; // h0 plane
        __align__(16) f16 planeB[8 * HP_STRIDE]; // h1 plane (L1 only)
        char  pad[60 * 1024];                    // force 1 WG/CU
    };
    __shared__ SM sm;
    const int tid = threadIdx.x;
    if (tid == 0x00FFFFFFu) sm.pad[0] = 1;       // keep pad alive

    const int bid  = blockIdx.x;
    const int g    = bid & 7;        // group (XCD-affine under round-robin)
    const int rk   = bid >> 3;       // 0..31 within group
    const int role = rk >> 4;        // 0: layer-0 WG, 1: layer-1 WG
    const int r    = rk & 15;        // rank within role
    const int w    = tid >> 6;       // wave id = gate type (i,f,g,o)
    const int lane = tid & 63;
    const int ln   = lane & 15;
    const int q    = lane >> 4;
    const int gb8  = g * 8;

    int* barb  = (int*)(ws + WS_FLAG_OFF) + g * 128;  // 512 B per group
    int* flag0 = barb;               // 16 per-L0-WG monotone step flags
    int* flag1 = barb + 64;          // 16 per-L1-WG flags (separate line)
    f16* H0g = (f16*)(ws + WS_H0_OFF) + g * 16384;  // 4 depth planes
    f16* H1g = (f16*)(ws + WS_H1_OFF) + g * 8192;   // 2 depth planes

    // ---- LDS init -------------------------------------------------------
    ((float*)sm.c)[tid] = 0.f;                   // 8*32 = 256 floats
    if (tid < 128) {
        int gate = tid >> 5, u = tid & 31;
        const float* bx = role ? bx1 : bx0;
        sm.bias[gate][u] = bx[(gate << 9) + (r << 5) + u];
    }

    // ---- persistent weight fragments in registers -----------------------
    // W[ ]: role 0 -> W[tau*17+kk] (K=544: Wh0|Wx0pad), tau in {0,1} n-tiles.
    //       role 1 -> W[tau*32+kk] (K=1024: Wx1|Wh1).
    f16x8 W[64];
    if (role == 0) {
#pragma unroll
        for (int tau = 0; tau < 2; ++tau) {
            const int rw = (w << 9) + (r << 5) + tau * 16 + ln;
            const float* wh0r = Wh0 + (size_t)rw * 512;
#pragma unroll
            for (int kk = 0; kk < 16; ++kk)
                W[tau * 17 + kk] = pack8(wh0r + kk * 32 + q * 8);
            const float* wx0r = Wx0 + (size_t)rw * 21;
            f16x8 f = {(_Float16)0, (_Float16)0, (_Float16)0, (_Float16)0,
                       (_Float16)0, (_Float16)0, (_Float16)0, (_Float16)0};
#pragma unroll
            for (int j = 0; j < 8; ++j) {
                int kl = q * 8 + j;
                if (kl < 21) f[j] = (f16)wx0r[kl];
            }
            W[tau * 17 + 16] = f;
        }
    } else {
#pragma unroll
        for (int tau = 0; tau < 2; ++tau) {
            const int rw = (w << 9) + (r << 5) + tau * 16 + ln;
            const float* wx1r = Wx1 + (size_t)rw * 512;
            const float* wh1r = Wh1 + (size_t)rw * 512;
#pragma unroll
            for (int kk = 0; kk < 16; ++kk)
                W[tau * 32 + kk] = pack8(wx1r + kk * 32 + q * 8);
#pragma unroll
            for (int kk = 16; kk < 32; ++kk)
                W[tau * 32 + kk] = pack8(wh1r + (kk - 16) * 32 + q * 8);
        }
    }
    __syncthreads();

    if (role == 0) {
        // =================== layer-0 pipeline stage =======================
        // Writes h0(t) -> plane t&3. Waits flag1 >= t-3 so h0(t-4)'s plane is
        // consumed before overwrite; runs up to 3 steps ahead of L1.
        long long ew = 0;                          // EWMA of blocked wait (clk)
        for (int t = 0; t < T_STEPS; ++t) {
            const int wr = t & 3, rd = (t + 3) & 3;
            f16x8 xf = load_xfrag(x, gb8, t, ln, q);   // prefetch before wait
            if (tid < 64) {
                long long d = wait_flags(flag0, t, flag1, t - 3, lane, ew);
                ew = ewma_upd(ew, d);
            }
            __syncthreads();                           // release waves 1-3
            stage_plane(H0g + rd * 4096, sm.planeA, tid);
            __syncthreads();

            f32x4 a0 = {0, 0, 0, 0}, a1 = {0, 0, 0, 0};
#pragma unroll
            for (int kk = 0; kk < 16; ++kk) {
                f16x8 A = afrag_lds(sm.planeA, kk * 32, ln, q);
                a0 = __builtin_amdgcn_mfma_f32_16x16x32_f16(A, W[kk], a0, 0, 0, 0);
                a1 = __builtin_amdgcn_mfma_f32_16x16x32_f16(A, W[17 + kk], a1, 0, 0, 0);
            }
            a0 = __builtin_amdgcn_mfma_f32_16x16x32_f16(xf, W[16], a0, 0, 0, 0);
            a1 = __builtin_amdgcn_mfma_f32_16x16x32_f16(xf, W[33], a1, 0, 0, 0);
            if (q < 2) {
#pragma unroll
                for (int r4 = 0; r4 < 4; ++r4) {
                    sm.g[w][q * 4 + r4][ln] = a0[r4];
                    sm.g[w][q * 4 + r4][16 + ln] = a1[r4];
                }
            }
            __syncthreads();
            {   // activation: 8 batches x 32 units = 256 threads
                int b = tid >> 5, u = tid & 31;
                float gi = sm.g[0][b][u] + sm.bias[0][u];
                float gf = sm.g[1][b][u] + sm.bias[1][u];
                float gg = sm.g[2][b][u] + sm.bias[2][u];
                float go = sm.g[3][b][u] + sm.bias[3][u];
                float iv = sigm_(gi), fv = sigm_(gf), gv = tanh_(gg), ov = sigm_(go);
                float c = sm.c[b][u];
                float cn = fv * c + iv * gv;
                sm.c[b][u] = cn;
                sm.hout[b][u] = (f16)(ov * tanh_(cn));
            }
            __syncthreads();
            if (tid < 64) {   // 512 B contiguous WG slice, wave-0 only
                int b = tid >> 3, j = tid & 7;
                u64 v = *(const u64*)&sm.hout[b][j * 4];
                __hip_atomic_store((u64*)(H0g + wr * 4096 + (r << 8) + (b << 5) + (j << 2)),
                                   v, __ATOMIC_RELAXED, __HIP_MEMORY_SCOPE_SYSTEM);
                asm volatile("s_waitcnt vmcnt(0)" ::: "memory");
                if (tid == 0)
                    __hip_atomic_store(flag0 + r, t + 1, __ATOMIC_RELAXED,
                                       __HIP_MEMORY_SCOPE_SYSTEM);
            }
        }
    } else {
        // =================== layer-1 pipeline stage =======================
        // MERGED: one wait (flag0>=t+1 && flag1>=t), one dual-plane staging
        // pass, then all 64 MFMAs (r13 structure).
        long long ew = 0;                          // EWMA of blocked wait (clk)
        for (int t = 0; t < T_STEPS; ++t) {
            const int wr = t & 1, rd = wr ^ 1;

            if (tid < 64) {
                long long d = wait_flags(flag0, t + 1, flag1, t, lane, ew);
                ew = ewma_upd(ew, d);
            }
            __syncthreads();
            stage_two(H0g + (t & 3) * 4096, sm.planeA,   // h0(t)
                      H1g + rd * 4096,      sm.planeB,   // h1(t-1)
                      tid);
            __syncthreads();

            f32x4 a0 = {0, 0, 0, 0}, a1 = {0, 0, 0, 0};
#pragma unroll
            for (int kk = 0; kk < 16; ++kk) {
                f16x8 A = afrag_lds(sm.planeA, kk * 32, ln, q);
                a0 = __builtin_amdgcn_mfma_f32_16x16x32_f16(A, W[kk], a0, 0, 0, 0);
                a1 = __builtin_amdgcn_mfma_f32_16x16x32_f16(A, W[32 + kk], a1, 0, 0, 0);
            }
#pragma unroll
            for (int kk = 16; kk < 32; ++kk) {
                f16x8 A = afrag_lds(sm.planeB, (kk - 16) * 32, ln, q);
                a0 = __builtin_amdgcn_mfma_f32_16x16x32_f16(A, W[kk], a0, 0, 0, 0);
                a1 = __builtin_amdgcn_mfma_f32_16x16x32_f16(A, W[32 + kk], a1, 0, 0, 0);
            }
            if (q < 2) {
#pragma unroll
                for (int r4 = 0; r4 < 4; ++r4) {
                    sm.g[w][q * 4 + r4][ln] = a0[r4];
                    sm.g[w][q * 4 + r4][16 + ln] = a1[r4];
                }
            }
            __syncthreads();
            {
                int b = tid >> 5, u = tid & 31;
                float gi = sm.g[0][b][u] + sm.bias[0][u];
                float gf = sm.g[1][b][u] + sm.bias[1][u];
                float gg = sm.g[2][b][u] + sm.bias[2][u];
                float go = sm.g[3][b][u] + sm.bias[3][u];
                float iv = sigm_(gi), fv = sigm_(gf), gv = tanh_(gg), ov = sigm_(go);
                float c = sm.c[b][u];
                float cn = fv * c + iv * gv;
                sm.c[b][u] = cn;
                sm.hout[b][u] = (f16)(ov * tanh_(cn));
            }
            __syncthreads();
            if (tid < 64) {
                int b = tid >> 3, j = tid & 7;
                u64 v = *(const u64*)&sm.hout[b][j * 4];
                __hip_atomic_store((u64*)(H1g + wr * 4096 + (r << 8) + (b << 5) + (j << 2)),
                                   v, __ATOMIC_RELAXED, __HIP_MEMORY_SCOPE_SYSTEM);
                asm volatile("s_waitcnt vmcnt(0)" ::: "memory");
                if (tid == 0)
                    __hip_atomic_store(flag1 + r, t + 1, __ATOMIC_RELAXED,
                                       __HIP_MEMORY_SCOPE_SYSTEM);
            }

            // ---- out-proj(t-1) AFTER publish, from LDS planeB (off the
            // inter-WG path; also hides peers' flag1 crossing for step t+1).
            // Safe: planeB's next overwrite is after the next wait's
            // __syncthreads, which orders it after these reads.
            if (t > 0) {
                int p = tid >> 4, kp = tid & 15;
                int valid = (p < 10);
                int idx = r * 10 + p;
                int b = valid ? idx / 20 : 0, o = valid ? idx % 20 : 0;
                float a = 0.f;
                if (valid) {
                    const f16* hp = sm.planeB + b * HP_STRIDE + kp * 32;
                    const float* wo = Wo + (size_t)o * 512 + kp * 32;
#pragma unroll
                    for (int k = 0; k < 32; k += 8) {
                        f16x8 hv = *(const f16x8*)(hp + k);
                        float4 wa = *(const float4*)(wo + k);
                        float4 wb = *(const float4*)(wo + k + 4);
                        a += (float)hv[0] * wa.x + (float)hv[1] * wa.y +
                             (float)hv[2] * wa.z + (float)hv[3] * wa.w +
                             (float)hv[4] * wb.x + (float)hv[5] * wb.y +
                             (float)hv[6] * wb.z + (float)hv[7] * wb.w;
                    }
                }
                a += __shfl_down(a, 8, 16);
                a += __shfl_down(a, 4, 16);
                a += __shfl_down(a, 2, 16);
                a += __shfl_down(a, 1, 16);
                if (valid && kp == 0)
                    out[((size_t)(gb8 + b) * 1024 + (t - 1)) * 20 + o] =
                        sigm_(a + bo[o]);
            }
        }

        // ===== epilogue: out(T-1) from h1(T-1) =============================
        if (tid < 64) wait_flags(flag1, T_STEPS, flag1, T_STEPS, lane, 0);
        __syncthreads();
        stage_plane(H1g + ((T_STEPS - 1) & 1) * 4096, sm.planeB, tid);
        __syncthreads();
        {
            int p = tid >> 4, kp = tid & 15;
            int valid = (p < 10);
            int idx = r * 10 + p;
            int b = valid ? idx / 20 : 0, o = valid ? idx % 20 : 0;
            float a = 0.f;
            if (valid) {
                const f16* hp = sm.planeB + b * HP_STRIDE + kp * 32;
                const float* wo = Wo + (size_t)o * 512 + kp * 32;
#pragma unroll
                for (int k = 0; k < 32; k += 8) {
                    f16x8 hv = *(const f16x8*)(hp + k);
                    float4 wa = *(const float4*)(wo + k);
                    float4 wb = *(const float4*)(wo + k + 4);
                    a += (float)hv[0] * wa.x + (float)hv[1] * wa.y +
                         (float)hv[2] * wa.z + (float)hv[3] * wa.w +
                         (float)hv[4] * wb.x + (float)hv[5] * wb.y +
                         (float)hv[6] * wb.z + (float)hv[7] * wb.w;
                }
            }
            a += __shfl_down(a, 8, 16);
            a += __shfl_down(a, 4, 16);
            a += __shfl_down(a, 2, 16);
            a += __shfl_down(a, 1, 16);
            if (valid && kp == 0)
                out[((size_t)(gb8 + b) * 1024 + (T_STEPS - 1)) * 20 + o] =
                    sigm_(a + bo[o]);
        }
    }
}

extern "C" void kernel_launch(void* const* d_in, const int* in_sizes, int n_in,
                              void* d_out, int out_size, void* d_ws, size_t ws_size,
                              hipStream_t stream) {
    const float* x   = (const float*)d_in[0];
    const float* Wx0 = (const float*)d_in[1];
    const float* bx0 = (const float*)d_in[2];
    const float* Wh0 = (const float*)d_in[3];
    const float* Wx1 = (const float*)d_in[4];
    const float* bx1 = (const float*)d_in[5];
    const float* Wh1 = (const float*)d_in[6];
    const float* Wo  = (const float*)d_in[7];
    const float* bo  = (const float*)d_in[8];
    float* out = (float*)d_out;
    char*  ws  = (char*)d_ws;

    if (ws_size < (size_t)WS_NEED) return;   // fail visibly (out stays poisoned)

    zero_ws_kernel<<<128, 256, 0, stream>>>((unsigned*)ws, WS_NEED / 4);
    lstm_persist<<<256, 256, 0, stream>>>(x, Wx0, bx0, Wh0, Wx1, bx1, Wh1,
                                          Wo, bo, out, ws);
}